// Round 5
// baseline (102.472 us; speedup 1.0000x reference)
//
#include <hip/hip_runtime.h>
#include <math.h>

#define EPS2f 0.25f
#define EPS4f 0.0625f

// ---------------------------------------------------------------------------
// Single fused kernel. Grid 256 x 1024 threads (16 waves, 1 block/CU).
// Block = 4 batch rows (b0..b0+3) x ALL 1024 (i,j) pairs.
//
// Inputs are tiny (8 KB each) -> stage S0/Mu0/S1/Mu1 in LDS and RECOMPUTE
// sigma / K / mu_t on the fly in both phases. No precompute kernel, no
// finalize kernel, no global table traffic (R4's 64 MB -> ~40 KB/block).
//
// Phase A: thread = ij, loop over k:  q_bb += (x-mu)^2/sigma, c += log sigma.
//          W = exp(clip(-0.5(q+c)))*Lam -> LDS (rows padded to 5 words).
// Phase B: wave w owns ij in [64w, 64w+64) = i in {2w,2w+1} x j=0..31,
//          lane = k. s0/m0 for the two i's preloaded in regs; one
//          ds_read_b64 of (s1,m1) per j serves both ij rows. Same-wave
//          producer/consumer for W -> no barrier between A and B.
// Epilogue: combine 16 waves' partials, divide, store directly to out.
// ---------------------------------------------------------------------------
__global__ __launch_bounds__(1024) void gmm_fused_kernel(
    const float* __restrict__ X,
    const float* __restrict__ Mu0, const float* __restrict__ Mu1,
    const float* __restrict__ S0,  const float* __restrict__ S1,
    const float* __restrict__ Lam, const float* __restrict__ tptr,
    float* __restrict__ out)
{
    __shared__ float2 SM0T[64 * 33];   // [k][i] = {S0, Mu0}, pad 33
    __shared__ float2 SM1T[64 * 33];   // [k][j] = {S1, Mu1}, pad 33
    __shared__ float4 Xs4[64];         // [k] = x for bb=0..3 (phase-A bcast)
    __shared__ float  XsT[4 * 64];     // [bb][k] (phase-B per-lane)
    __shared__ float  Wl[1024 * 5];    // [ij][bb], rows of 5: conflict-free
    __shared__ float  red[16 * 64 * 5];// [w][k][bb], rows of 5
    __shared__ float  denp[16 * 4];    // per-wave per-bb den partials

    const int tid  = threadIdx.x;
    const int lane = tid & 63;
    const int w    = tid >> 6;         // 0..15
    const int b0   = blockIdx.x << 2;

    // ---- Stage inputs ----
    for (int e = tid; e < 2048; e += 1024) {      // 32x64 each, coalesced
        const int i = e >> 6, k = e & 63;
        SM0T[k * 33 + i] = make_float2(S0[e], Mu0[e]);
        SM1T[k * 33 + i] = make_float2(S1[e], Mu1[e]);
    }
    if (tid < 256) {
        const int bb = tid >> 6, k = tid & 63;
        const float xv = X[(b0 + bb) * 64 + k];
        ((float*)&Xs4[k])[bb] = xv;
        XsT[bb * 64 + k] = xv;
    }

    const float t    = *tptr;          // uniform -> scalar load
    const float omt  = 1.0f - t;
    const float omt2 = omt * omt, tt = t * t, tt2 = 2.0f * t * omt;
    const float ctt  = tt2 * 0.125f;   // tt2 * (0.5*eps2)
    const float sc   = omt - t;        // (1-2t), coefficient of Cs in St
    const float ce   = -EPS2f * t;     // constant term in St

    __syncthreads();

    // ---- Phase A: thread = ij ----
    const int ij = tid;
    const int ii = ij >> 5, jj = ij & 31;
    float q0 = 0.f, q1 = 0.f, q2 = 0.f, q3 = 0.f, csum = 0.f;
    #pragma unroll 4
    for (int k = 0; k < 64; ++k) {
        const float2 sm0 = SM0T[k * 33 + ii];   // 2 addrs/wave: broadcast
        const float2 sm1 = SM1T[k * 33 + jj];   // 32 addrs: floor-limited b64
        const float4 x   = Xs4[k];              // broadcast b128
        const float s0 = sm0.x, m0 = sm0.y, s1 = sm1.x, m1 = sm1.y;
        const float ds   = sqrtf(fmaf(4.0f * s0, s1, EPS4f));
        const float cs   = fmaf(0.5f, ds, -0.125f);
        const float sig  = fmaf(tt2, cs, fmaf(tt, s1, fmaf(omt2, s0, ctt)));
        const float isig = __builtin_amdgcn_rcpf(sig);
        const float mt   = fmaf(omt, m0, t * m1);
        csum += __logf(sig);
        float dd;
        dd = x.x - mt; q0 = fmaf(dd * isig, dd, q0);
        dd = x.y - mt; q1 = fmaf(dd * isig, dd, q1);
        dd = x.z - mt; q2 = fmaf(dd * isig, dd, q2);
        dd = x.w - mt; q3 = fmaf(dd * isig, dd, q3);
    }
    const float lm = Lam[ij];
    #define WCALC(q) (__expf(fminf(fmaxf(-0.5f * ((q) + csum), -50.f), 50.f)) * lm)
    const float w0 = WCALC(q0), w1 = WCALC(q1), w2 = WCALC(q2), w3 = WCALC(q3);
    #undef WCALC
    Wl[ij * 5 + 0] = w0; Wl[ij * 5 + 1] = w1;
    Wl[ij * 5 + 2] = w2; Wl[ij * 5 + 3] = w3;

    float d0 = w0, d1 = w1, d2 = w2, d3 = w3;
    #pragma unroll
    for (int off = 32; off >= 1; off >>= 1) {
        d0 += __shfl_xor(d0, off, 64);
        d1 += __shfl_xor(d1, off, 64);
        d2 += __shfl_xor(d2, off, 64);
        d3 += __shfl_xor(d3, off, 64);
    }
    if (lane == 0) {
        denp[w * 4 + 0] = d0; denp[w * 4 + 1] = d1;
        denp[w * 4 + 2] = d2; denp[w * 4 + 3] = d3;
    }

    // ---- Phase B: wave w, lane = k; i in {2w, 2w+1}, j = 0..31 ----
    // (Wl rows [64w, 64w+64) were written by this same wave: no barrier.)
    const int i0 = w << 1;
    const float2 a0 = SM0T[lane * 33 + i0];
    const float2 a1 = SM0T[lane * 33 + i0 + 1];
    const float xk0 = XsT[0 * 64 + lane], xk1 = XsT[1 * 64 + lane];
    const float xk2 = XsT[2 * 64 + lane], xk3 = XsT[3 * 64 + lane];
    float n0 = 0.f, n1 = 0.f, n2 = 0.f, n3 = 0.f;

    #pragma unroll 4
    for (int j = 0; j < 32; ++j) {
        const float2 sm1 = SM1T[lane * 33 + j];
        const float s1 = sm1.x, m1 = sm1.y;
        {   // ij_a = w*64 + j   (i = 2w)
            const float s0 = a0.x, m0 = a0.y;
            const float ds   = sqrtf(fmaf(4.0f * s0, s1, EPS4f));
            const float cs   = fmaf(0.5f, ds, -0.125f);
            const float sig  = fmaf(tt2, cs, fmaf(tt, s1, fmaf(omt2, s0, ctt)));
            const float isig = __builtin_amdgcn_rcpf(sig);
            const float st   = fmaf(sc, cs, fmaf(-omt, s0, fmaf(t, s1, ce)));
            const float kk   = st * isig;
            const float mt   = fmaf(omt, m0, t * m1);
            const float vm   = fmaf(-kk, mt, m1 - m0);
            const int ra = (w * 64 + j) * 5;          // broadcast reads
            float u;
            u = fmaf(kk, xk0, vm); n0 = fmaf(Wl[ra + 0], u, n0);
            u = fmaf(kk, xk1, vm); n1 = fmaf(Wl[ra + 1], u, n1);
            u = fmaf(kk, xk2, vm); n2 = fmaf(Wl[ra + 2], u, n2);
            u = fmaf(kk, xk3, vm); n3 = fmaf(Wl[ra + 3], u, n3);
        }
        {   // ij_b = w*64 + 32 + j   (i = 2w+1)
            const float s0 = a1.x, m0 = a1.y;
            const float ds   = sqrtf(fmaf(4.0f * s0, s1, EPS4f));
            const float cs   = fmaf(0.5f, ds, -0.125f);
            const float sig  = fmaf(tt2, cs, fmaf(tt, s1, fmaf(omt2, s0, ctt)));
            const float isig = __builtin_amdgcn_rcpf(sig);
            const float st   = fmaf(sc, cs, fmaf(-omt, s0, fmaf(t, s1, ce)));
            const float kk   = st * isig;
            const float mt   = fmaf(omt, m0, t * m1);
            const float vm   = fmaf(-kk, mt, m1 - m0);
            const int rb = (w * 64 + 32 + j) * 5;
            float u;
            u = fmaf(kk, xk0, vm); n0 = fmaf(Wl[rb + 0], u, n0);
            u = fmaf(kk, xk1, vm); n1 = fmaf(Wl[rb + 1], u, n1);
            u = fmaf(kk, xk2, vm); n2 = fmaf(Wl[rb + 2], u, n2);
            u = fmaf(kk, xk3, vm); n3 = fmaf(Wl[rb + 3], u, n3);
        }
    }
    {
        float* r = &red[(w * 64 + lane) * 5];
        r[0] = n0; r[1] = n1; r[2] = n2; r[3] = n3;
    }
    __syncthreads();

    // ---- Epilogue: tid<256, bb = tid>>6 (wave-uniform), k = tid&63 ----
    if (tid < 256) {
        const int bb = tid >> 6, k = tid & 63;
        float s = 0.f, d = 0.f;
        #pragma unroll
        for (int ww = 0; ww < 16; ++ww) {
            s += red[(ww * 64 + k) * 5 + bb];
            d += denp[ww * 4 + bb];
        }
        out[(b0 + bb) * 64 + k] = s / d;
    }
}

extern "C" void kernel_launch(void* const* d_in, const int* in_sizes, int n_in,
                              void* d_out, int out_size, void* d_ws, size_t ws_size,
                              hipStream_t stream) {
    const float* X   = (const float*)d_in[0];
    const float* Mu0 = (const float*)d_in[1];
    const float* Mu1 = (const float*)d_in[2];
    const float* S0  = (const float*)d_in[3];
    const float* S1  = (const float*)d_in[4];
    const float* Lam = (const float*)d_in[5];
    const float* t   = (const float*)d_in[6];
    float* out = (float*)d_out;

    gmm_fused_kernel<<<256, 1024, 0, stream>>>(X, Mu0, Mu1, S0, S1, Lam, t, out);
}

// Round 6
// 79.405 us; speedup vs baseline: 1.2905x; 1.2905x over previous
//
#include <hip/hip_runtime.h>
#include <math.h>

#define EPS2f 0.25f
#define EPS4f 0.0625f

// ---------------------------------------------------------------------------
// Kernel 1: precompute per-(ij,k) tables (~3 us; pays all transcendentals ONCE
// instead of once per block as in round 5's fused kernel, which was VALU-bound
// at 72% / 44.8 us on redundant sqrt/rcp/log).
//   AB4 (float4 view)[k2*1024 + ij] = { A(2k2), B2(2k2), A(2k2+1), B2(2k2+1) }
//        A = 1/Sigma, B2 = 2*mu_t/Sigma
//   KV4 (float4 view)[ij2*64 + k]   = { K(ij_e), Vm(ij_e), K(ij_o), Vm(ij_o) }
//        pair-packed: ij_e = 2*ij2, ij_o = 2*ij2+1  (one dwordx4 serves 2 ij)
//   C0 [ij] = sum_k ( mu_t^2/Sigma + log(Sigma) )
// ---------------------------------------------------------------------------
__global__ __launch_bounds__(256) void precomp_kernel(
    const float* __restrict__ Mu0, const float* __restrict__ Mu1,
    const float* __restrict__ S0,  const float* __restrict__ S1,
    const float* __restrict__ tptr,
    float2* __restrict__ AB2, float2* __restrict__ KV2,
    float* __restrict__ C0)
{
    const int tid = threadIdx.x;
    const int k   = tid & 63;
    const int ij  = (blockIdx.x << 2) + (tid >> 6);
    const int i   = ij >> 5;              // N0=32
    const int j   = ij & 31;              // N1=32
    const float t   = *tptr;
    const float omt = 1.0f - t;

    const float s0 = S0[i * 64 + k];
    const float s1 = S1[j * 64 + k];
    const float m0 = Mu0[i * 64 + k];
    const float m1 = Mu1[j * 64 + k];

    const float ds  = sqrtf(4.0f * s0 * s1 + EPS4f);
    const float cs  = 0.5f * (ds - EPS2f);
    const float mt  = omt * m0 + t * m1;
    const float sig = omt * omt * s0 + t * t * s1
                    + 2.0f * t * omt * (cs + 0.5f * EPS2f);
    const float isig = 1.0f / sig;
    const float st = t * s1 - omt * s0 + (omt - t) * cs - EPS2f * t;
    const float kk = st * isig;
    const float v  = m1 - m0;

    AB2[((k >> 1) << 11) + (ij << 1) + (k & 1)] = make_float2(isig, 2.0f * mt * isig);
    // pair-packed KV: float2 slot (ij>>1)*128 + k*2 + (ij&1)
    KV2[((ij >> 1) << 7) + (k << 1) + (ij & 1)] = make_float2(kk, v - kk * mt);

    float c = mt * mt * isig + __logf(sig);
    #pragma unroll
    for (int off = 32; off >= 1; off >>= 1)
        c += __shfl_xor(c, off, 64);
    if (k == 0) C0[ij] = c;
}

// ---------------------------------------------------------------------------
// Kernel 2: main. Block = 4 batch rows x all 1024 ij. 1024 threads = 16 waves.
// Phase A: thread = ij; 32 iters x {1 dwordx4 table load + 16 FMA};
//          unroll 8 -> ~8 outstanding L2 loads/wave hides ~200cyc latency.
// Phase B: wave w owns ij [64w, 64w+64) as 32 even/odd pairs; lane = k;
//          32 iters x {1 dwordx4 KV + 2 ds_read_b128 (broadcast) + 16 FMA}.
//          Same-wave producer/consumer for Wl -> no barrier between A and B.
// ---------------------------------------------------------------------------
__global__ __launch_bounds__(1024) void gmm_main_kernel(
    const float* __restrict__ X,   const float* __restrict__ Lam,
    const float* __restrict__ C0,
    const float4* __restrict__ AB4, const float4* __restrict__ KV4,
    float* __restrict__ out)
{
    __shared__ float4 Xs4[64];           // [k] = x for bb=0..3 (bcast b128)
    __shared__ float4 Wl4[1024 * 2];     // [ij][2]: slot 0 = W for bb=0..3
    __shared__ float  red[16 * 64 * 5];  // [w][k][bb], stride 5: conflict-free
    __shared__ float  XsT[4 * 64];       // [bb][k]
    __shared__ float  denp[16 * 4];      // per-wave per-bb den partials

    const int tid  = threadIdx.x;
    const int lane = tid & 63;
    const int w    = tid >> 6;           // 0..15
    const int b0   = blockIdx.x << 2;

    if (tid < 256) {
        const int bb = tid >> 6, k = tid & 63;
        const float xv = X[(b0 + bb) * 64 + k];
        ((float*)&Xs4[k])[bb] = xv;
        XsT[bb * 64 + k] = xv;
    }
    __syncthreads();

    // ---- Phase A: one ij per thread ----
    const int ij = tid;
    const float c0 = C0[ij];             // hoisted: overlaps with loop
    const float lm = Lam[ij];
    float qa = 0.f, qb = 0.f, qc = 0.f, qd = 0.f;
    #pragma unroll 8
    for (int k2 = 0; k2 < 32; ++k2) {
        const float4 ab = AB4[(k2 << 10) + ij];   // coalesced 16B/lane
        const float4 x0 = Xs4[2 * k2];            // LDS broadcast
        const float4 x1 = Xs4[2 * k2 + 1];
        qa = fmaf(fmaf(ab.x, x0.x, -ab.y), x0.x, qa);
        qb = fmaf(fmaf(ab.x, x0.y, -ab.y), x0.y, qb);
        qc = fmaf(fmaf(ab.x, x0.z, -ab.y), x0.z, qc);
        qd = fmaf(fmaf(ab.x, x0.w, -ab.y), x0.w, qd);
        qa = fmaf(fmaf(ab.z, x1.x, -ab.w), x1.x, qa);
        qb = fmaf(fmaf(ab.z, x1.y, -ab.w), x1.y, qb);
        qc = fmaf(fmaf(ab.z, x1.z, -ab.w), x1.z, qc);
        qd = fmaf(fmaf(ab.z, x1.w, -ab.w), x1.w, qd);
    }

    #define WCALC(q) (__expf(fminf(fmaxf(-0.5f * ((q) + c0), -50.f), 50.f)) * lm)
    float4 wv4;
    wv4.x = WCALC(qa); wv4.y = WCALC(qb); wv4.z = WCALC(qc); wv4.w = WCALC(qd);
    #undef WCALC
    Wl4[ij * 2] = wv4;                   // aligned 16B row -> ds_read_b128 later

    float d0 = wv4.x, d1 = wv4.y, d2 = wv4.z, d3 = wv4.w;
    #pragma unroll
    for (int off = 32; off >= 1; off >>= 1) {
        d0 += __shfl_xor(d0, off, 64);
        d1 += __shfl_xor(d1, off, 64);
        d2 += __shfl_xor(d2, off, 64);
        d3 += __shfl_xor(d3, off, 64);
    }
    if (lane == 0) {
        denp[w * 4 + 0] = d0; denp[w * 4 + 1] = d1;
        denp[w * 4 + 2] = d2; denp[w * 4 + 3] = d3;
    }

    // ---- Phase B: wave w, 32 ij-pairs, lane = k ----
    // (Wl rows [64w, 64w+64) written by this same wave: no barrier needed.)
    const float xk0 = XsT[0 * 64 + lane], xk1 = XsT[1 * 64 + lane];
    const float xk2 = XsT[2 * 64 + lane], xk3 = XsT[3 * 64 + lane];
    float n0 = 0.f, n1 = 0.f, n2 = 0.f, n3 = 0.f;
    const int p0 = w << 5;               // first pair index of this wave
    #pragma unroll 8
    for (int p = 0; p < 32; ++p) {
        const float4 kv = KV4[((p0 + p) << 6) + lane]; // {K_e,V_e,K_o,V_o} 16B
        const float4 we = Wl4[(p0 + p) * 4];           // ij_e = 2*(p0+p)
        const float4 wo = Wl4[(p0 + p) * 4 + 2];       // ij_o
        float u;
        u = fmaf(kv.x, xk0, kv.y); n0 = fmaf(we.x, u, n0);
        u = fmaf(kv.x, xk1, kv.y); n1 = fmaf(we.y, u, n1);
        u = fmaf(kv.x, xk2, kv.y); n2 = fmaf(we.z, u, n2);
        u = fmaf(kv.x, xk3, kv.y); n3 = fmaf(we.w, u, n3);
        u = fmaf(kv.z, xk0, kv.w); n0 = fmaf(wo.x, u, n0);
        u = fmaf(kv.z, xk1, kv.w); n1 = fmaf(wo.y, u, n1);
        u = fmaf(kv.z, xk2, kv.w); n2 = fmaf(wo.z, u, n2);
        u = fmaf(kv.z, xk3, kv.w); n3 = fmaf(wo.w, u, n3);
    }
    {
        float* r = &red[(w * 64 + lane) * 5];
        r[0] = n0; r[1] = n1; r[2] = n2; r[3] = n3;
    }
    __syncthreads();

    // ---- Epilogue ----
    if (tid < 256) {
        const int bb = tid >> 6, k = tid & 63;   // bb wave-uniform
        float s = 0.f, d = 0.f;
        #pragma unroll
        for (int ww = 0; ww < 16; ++ww) {
            s += red[(ww * 64 + k) * 5 + bb];
            d += denp[ww * 4 + bb];
        }
        out[(b0 + bb) * 64 + k] = s / d;
    }
}

extern "C" void kernel_launch(void* const* d_in, const int* in_sizes, int n_in,
                              void* d_out, int out_size, void* d_ws, size_t ws_size,
                              hipStream_t stream) {
    const float* X   = (const float*)d_in[0];
    const float* Mu0 = (const float*)d_in[1];
    const float* Mu1 = (const float*)d_in[2];
    const float* S0  = (const float*)d_in[3];
    const float* S1  = (const float*)d_in[4];
    const float* Lam = (const float*)d_in[5];
    const float* t   = (const float*)d_in[6];
    float* out = (float*)d_out;

    char* ws = (char*)d_ws;
    float2* AB2 = (float2*)(ws);                  // 512 KiB
    float2* KV2 = (float2*)(ws + (512 << 10));    // 512 KiB
    float*  C0  = (float*)(ws + (1024 << 10));    // 4 KiB

    precomp_kernel<<<256, 256, 0, stream>>>(Mu0, Mu1, S0, S1, t, AB2, KV2, C0);
    gmm_main_kernel<<<256, 1024, 0, stream>>>(X, Lam, C0,
                                              (const float4*)AB2,
                                              (const float4*)KV2, out);
}